// Round 15
// baseline (60.328 us; speedup 1.0000x reference)
//
#include <hip/hip_runtime.h>
#include <hip/hip_bf16.h>
#include <math.h>

#define NFREQ 1024      // N_FFT//2
#define NMELS 256
#define NNOTES 82
#define KPAD  96        // K padded to multiple of 32 for mfma 16x16x32
#define KMAXH 400

#define TROWS 32
#define TFLOAT (TROWS * NNOTES)
#define BUFSTRIDE (TFLOAT + 16)

typedef __attribute__((ext_vector_type(8))) short bf16x8;
typedef __attribute__((ext_vector_type(4))) float f32x4;

__device__ inline unsigned short f2bf(float x) {
    union { float f; unsigned int u; } c; c.f = x;
    unsigned int r = c.u + 0x7FFFu + ((c.u >> 16) & 1u);   // round-to-nearest-even
    return (unsigned short)(r >> 16);
}

// ------------- Kernel AB (merged): harmonic cols (LDS) -> mel -> log -> bf16 ----
__global__ __launch_bounds__(256) void harm_prep(
    const float* __restrict__ omega,
    const float* __restrict__ stdv,
    const float* __restrict__ mask,
    unsigned short* __restrict__ wT)
{
    int n   = blockIdx.x;            // 0..95 (82..95 = K-pad rows)
    int tid = threadIdx.x;
    if (n >= NNOTES) {               // zero pad rows: (k>=82) x (any y bits) = 0
        wT[tid * KPAD + n] = 0;
        return;
    }
    __shared__ float cols[NFREQ];

    float f0 = 27.5f * exp2f((float)n / 12.0f);
    for (int fi = tid; fi < NFREQ; fi += 256) {
        float f = 11025.0f * (float)fi / 1023.0f;
        const float RAD = 80.0f;                           // 16*sigma at sigma=5
        int klo = (int)ceilf((f - RAD) / f0);
        int khi = (int)floorf((f + RAD) / f0);
        if (klo < 1) klo = 1;
        if (khi > KMAXH) khi = KMAXH;
        float acc = 0.0f;
        for (int k = klo; k <= khi; ++k) {
            int idx = n * KMAXH + (k - 1);
            float mk = mask[idx];
            if (mk == 0.0f) continue;
            float c = f0 * (float)k;
            float s = stdv[idx];
            float d = (f - c) / s;
            float e = 0.5f * d * d;
            if (e > 90.0f) continue;
            acc += omega[idx] * mk * expf(-e);
        }
        cols[fi] = acc;
    }
    __syncthreads();

    int m = tid;
    const float logstep = 0.06875177742094911f;            // log(6.4)/27
    const float mel_max = 15.0f + logf(11.025f) / logstep; // hz_to_mel(11025)
    float mm0 = mel_max * (float)m       / 257.0f;
    float mm1 = mel_max * (float)(m + 1) / 257.0f;
    float mm2 = mel_max * (float)(m + 2) / 257.0f;
    float mf0 = (mm0 >= 15.0f) ? 1000.0f * expf(logstep * (mm0 - 15.0f)) : mm0 * (200.0f / 3.0f);
    float mf1 = (mm1 >= 15.0f) ? 1000.0f * expf(logstep * (mm1 - 15.0f)) : mm1 * (200.0f / 3.0f);
    float mf2 = (mm2 >= 15.0f) ? 1000.0f * expf(logstep * (mm2 - 15.0f)) : mm2 * (200.0f / 3.0f);
    float inv_lo = 1.0f / (mf1 - mf0);
    float inv_hi = 1.0f / (mf2 - mf1);
    float enorm  = 2.0f / (mf2 - mf0);
    int lo = (int)floorf(mf0 * (1024.0f / 11025.0f)) - 1;
    int hi = (int)ceilf (mf2 * (1024.0f / 11025.0f)) + 1;
    if (lo < 0) lo = 0;
    if (hi > 1023) hi = 1023;
    float acc = 0.0f;
    for (int fi = lo; fi <= hi; ++fi) {
        float ff = 11025.0f * (float)(fi + 1) / 1024.0f;
        float wt = fminf((ff - mf0) * inv_lo, (mf2 - ff) * inv_hi);
        wt = fmaxf(0.0f, wt) * enorm;
        acc += wt * cols[fi];
    }
    const float X_MIN = -13.815510557964274f;              // log(1e-6)
    const float X_MAX = 3.0f;
    float x = logf(acc + 1e-6f);
    x = fminf(fmaxf(x, X_MIN), X_MAX);
    wT[m * KPAD + n] = f2bf((x - X_MIN) * (1.0f / (X_MAX - X_MIN)));
}

// ---------------- k1: y f32 -> pre-swizzled bf16 fragment array (copy-shaped) ---
// 192-thread block = one 16-row tile (3 kb x 64 lanes). Lane l of fragment
// (t,kb) holds y[t*16 + (l&15)][kb*32 + (l>>4)*8 .. +8] as bf16x8; k>=82 pairs
// are zeroed (they multiply zeroed wT pad rows in k2 anyway, but keep clean).
// Stores: consecutive tid -> consecutive 16B -> perfectly coalesced.
__global__ __launch_bounds__(192) void harm_swz(
    const float* __restrict__ y,
    bf16x8* __restrict__ ytmp)
{
    int t   = blockIdx.x;
    int kb  = threadIdx.x >> 6;
    int l   = threadIdx.x & 63;
    int r16 = l & 15;
    int g4  = l >> 4;
    int k0  = kb * 32 + g4 * 8;
    const float* src = y + ((size_t)t * 16 + r16) * NNOTES + k0;
    union { unsigned u[4]; bf16x8 v; } A;
    #pragma unroll
    for (int q = 0; q < 4; ++q) {
        float2 a = (k0 + 2 * q + 1 < NNOTES) ? *(const float2*)(src + 2 * q)
                                             : make_float2(0.f, 0.f);
        asm("v_cvt_pk_bf16_f32 %0, %1, %2" : "=v"(A.u[q]) : "v"(a.x), "v"(a.y));
    }
    ytmp[((size_t)t * 3 + kb) * 64 + l] = A.v;
}

// ---------------- k2: out = ytmp @ w (fill-shaped: 87% write) -------------------
// No LDS, no barriers, no cvt. 12 w-fragments in regs (loaded once per block);
// per 16-row tile: 3 coalesced dwordx4 ay loads (sister waves share via L1) +
// 12 MFMA + 4 f32x4 stores. 4 tiles per block, grid 2048 -> 8 blocks/CU.
__global__ __launch_bounds__(256) void harm_gemm2(
    const bf16x8* __restrict__ ytmp,
    const unsigned short* __restrict__ wT,
    float* __restrict__ out)
{
    int tid  = threadIdx.x;
    int lane = tid & 63;
    int wid  = tid >> 6;
    int r16  = lane & 15;
    int g4   = lane >> 4;
    int c0   = wid * 64;

    bf16x8 bw[3][4];
    #pragma unroll
    for (int kb = 0; kb < 3; ++kb)
        #pragma unroll
        for (int c = 0; c < 4; ++c)
            bw[kb][c] = *(const bf16x8*)(wT + (size_t)(c0 + c * 16 + r16) * KPAD + kb * 32 + g4 * 8);

    size_t tb = (size_t)blockIdx.x * 4;
    #pragma unroll
    for (int i = 0; i < 4; ++i) {
        size_t t = tb + i;
        bf16x8 ay0 = ytmp[(t * 3 + 0) * 64 + lane];
        bf16x8 ay1 = ytmp[(t * 3 + 1) * 64 + lane];
        bf16x8 ay2 = ytmp[(t * 3 + 2) * 64 + lane];
        f32x4 acc[4];
        #pragma unroll
        for (int c = 0; c < 4; ++c) acc[c] = (f32x4){0.f, 0.f, 0.f, 0.f};
        #pragma unroll
        for (int c = 0; c < 4; ++c) acc[c] = __builtin_amdgcn_mfma_f32_16x16x32_bf16(bw[0][c], ay0, acc[c], 0, 0, 0);
        #pragma unroll
        for (int c = 0; c < 4; ++c) acc[c] = __builtin_amdgcn_mfma_f32_16x16x32_bf16(bw[1][c], ay1, acc[c], 0, 0, 0);
        #pragma unroll
        for (int c = 0; c < 4; ++c) acc[c] = __builtin_amdgcn_mfma_f32_16x16x32_bf16(bw[2][c], ay2, acc[c], 0, 0, 0);
        // lane holds out[row = t*16 + r16][col = c0 + c*16 + g4*4 .. +3]
        float* orow = out + (t * 16 + r16) * NMELS + c0 + g4 * 4;
        #pragma unroll
        for (int c = 0; c < 4; ++c)
            *(f32x4*)(orow + c * 16) = acc[c];
    }
}

// ---------------- fallback: r13's fused rolling pipeline (if ws too small) ------
__device__ __forceinline__ void gload16(const void* g, void* l) {
    __builtin_amdgcn_global_load_lds(
        (const __attribute__((address_space(1))) unsigned int*)g,
        (__attribute__((address_space(3))) unsigned int*)l, 16, 0, 0);
}

__device__ __forceinline__ void dma_tile(const float* ytile, float* buf, int wid, int lane) {
    int base = wid * 164;
    gload16(ytile + 4 * (base + lane),       buf + 4 * base);
    gload16(ytile + 4 * (base + 64 + lane),  buf + 4 * (base + 64));
    if (lane < 36)
        gload16(ytile + 4 * (base + 128 + lane), buf + 4 * (base + 128));
}

__device__ __forceinline__ void compute_tile32(
    const float* __restrict__ bufp, const bf16x8 bw[3][4],
    float* __restrict__ out, size_t rowbase, int r16, int g4, int c0)
{
    #pragma unroll
    for (int i = 0; i < 2; ++i) {
        const float* yrow = bufp + (i * 16 + r16) * NNOTES;
        bf16x8 ay[3];
        #pragma unroll
        for (int kb = 0; kb < 3; ++kb) {
            const float* fr = yrow + kb * 32 + g4 * 8;
            float2 a0 = *(const float2*)(fr + 0);
            float2 a1 = *(const float2*)(fr + 2);
            float2 a2 = *(const float2*)(fr + 4);
            float2 a3 = *(const float2*)(fr + 6);
            union { unsigned u[4]; bf16x8 v; } A;
            asm("v_cvt_pk_bf16_f32 %0, %1, %2" : "=v"(A.u[0]) : "v"(a0.x), "v"(a0.y));
            asm("v_cvt_pk_bf16_f32 %0, %1, %2" : "=v"(A.u[1]) : "v"(a1.x), "v"(a1.y));
            asm("v_cvt_pk_bf16_f32 %0, %1, %2" : "=v"(A.u[2]) : "v"(a2.x), "v"(a2.y));
            asm("v_cvt_pk_bf16_f32 %0, %1, %2" : "=v"(A.u[3]) : "v"(a3.x), "v"(a3.y));
            ay[kb] = A.v;
        }
        f32x4 acc[4];
        #pragma unroll
        for (int c = 0; c < 4; ++c) acc[c] = (f32x4){0.f, 0.f, 0.f, 0.f};
        #pragma unroll
        for (int kb = 0; kb < 3; ++kb)
            #pragma unroll
            for (int c = 0; c < 4; ++c)
                acc[c] = __builtin_amdgcn_mfma_f32_16x16x32_bf16(bw[kb][c], ay[kb], acc[c], 0, 0, 0);
        float* orow = out + (rowbase + i * 16 + r16) * NMELS + c0 + g4 * 4;
        #pragma unroll
        for (int c = 0; c < 4; ++c)
            *(f32x4*)(orow + c * 16) = acc[c];
    }
}

#define SBAR() do { __builtin_amdgcn_sched_barrier(0); \
                    __builtin_amdgcn_s_barrier(); \
                    __builtin_amdgcn_sched_barrier(0); } while (0)

__global__ __launch_bounds__(256, 4) void harm_gemm(
    const float* __restrict__ y,
    const unsigned short* __restrict__ wT,
    float* __restrict__ out)
{
    __shared__ float yf[3 * BUFSTRIDE];
    int tid  = threadIdx.x;
    int lane = tid & 63;
    int wid  = tid >> 6;
    int r16  = lane & 15;
    int g4   = lane >> 4;
    int c0   = wid * 64;
    size_t t0 = (size_t)blockIdx.x * 4;

    if (tid < 48) yf[(tid >> 4) * BUFSTRIDE + TFLOAT + (tid & 15)] = 0.f;

    bf16x8 bw[3][4];
    #pragma unroll
    for (int kb = 0; kb < 3; ++kb)
        #pragma unroll
        for (int c = 0; c < 4; ++c)
            bw[kb][c] = *(const bf16x8*)(wT + (size_t)(c0 + c * 16 + r16) * KPAD + kb * 32 + g4 * 8);
    __builtin_amdgcn_sched_barrier(0);
    dma_tile(y + (t0 + 0) * TFLOAT, yf + 0 * BUFSTRIDE, wid, lane);
    __builtin_amdgcn_sched_barrier(0);
    dma_tile(y + (t0 + 1) * TFLOAT, yf + 1 * BUFSTRIDE, wid, lane);
    __builtin_amdgcn_sched_barrier(0);

    asm volatile("s_waitcnt vmcnt(3) lgkmcnt(0)" ::: "memory");
    SBAR();
    dma_tile(y + (t0 + 2) * TFLOAT, yf + 2 * BUFSTRIDE, wid, lane);
    __builtin_amdgcn_sched_barrier(0);
    compute_tile32(yf + 0 * BUFSTRIDE, bw, out, (t0 + 0) * TROWS, r16, g4, c0);

    asm volatile("s_waitcnt vmcnt(11)" ::: "memory");
    SBAR();
    dma_tile(y + (t0 + 3) * TFLOAT, yf + 0 * BUFSTRIDE, wid, lane);
    __builtin_amdgcn_sched_barrier(0);
    compute_tile32(yf + 1 * BUFSTRIDE, bw, out, (t0 + 1) * TROWS, r16, g4, c0);

    asm volatile("s_waitcnt vmcnt(19)" ::: "memory");
    SBAR();
    compute_tile32(yf + 2 * BUFSTRIDE, bw, out, (t0 + 2) * TROWS, r16, g4, c0);

    asm volatile("s_waitcnt vmcnt(16)" ::: "memory");
    SBAR();
    compute_tile32(yf + 0 * BUFSTRIDE, bw, out, (t0 + 3) * TROWS, r16, g4, c0);
}

extern "C" void kernel_launch(void* const* d_in, const int* in_sizes, int n_in,
                              void* d_out, int out_size, void* d_ws, size_t ws_size,
                              hipStream_t stream) {
    const float* y     = (const float*)d_in[0];
    const float* omega = (const float*)d_in[1];
    const float* stdv  = (const float*)d_in[2];
    const float* mask  = (const float*)d_in[3];
    float* out = (float*)d_out;

    unsigned short* wT = (unsigned short*)d_ws;           // 256*96 bf16 = 48 KB
    int R      = in_sizes[0] / NNOTES;                    // 131072 rows
    int ntiles = R / 16;                                  // 8192
    size_t wT_bytes   = (size_t)NMELS * KPAD * 2;
    size_t ytmp_bytes = (size_t)ntiles * 3 * 64 * 16;     // 25.2 MB
    bf16x8* ytmp = (bf16x8*)((char*)d_ws + wT_bytes);

    harm_prep<<<KPAD, 256, 0, stream>>>(omega, stdv, mask, wT);

    if (ws_size >= wT_bytes + ytmp_bytes) {
        harm_swz <<<ntiles,     192, 0, stream>>>(y, ytmp);
        harm_gemm2<<<ntiles / 4, 256, 0, stream>>>(ytmp, wT, out);
    } else {
        harm_gemm<<<R / 128, 256, 0, stream>>>(y, wT, out);  // r13 fallback
    }
}

// Round 16
// 56.178 us; speedup vs baseline: 1.0739x; 1.0739x over previous
//
#include <hip/hip_runtime.h>
#include <hip/hip_bf16.h>
#include <math.h>

#define NFREQ 1024      // N_FFT//2
#define NMELS 256
#define NNOTES 82
#define KPAD  96        // K padded to multiple of 32 for mfma 16x16x32
#define KMAXH 400

#define TROWS 32
#define TFLOAT (TROWS * NNOTES)
#define BUFSTRIDE (TFLOAT + 16)

typedef __attribute__((ext_vector_type(8))) short bf16x8;
typedef __attribute__((ext_vector_type(4))) float f32x4;

__device__ inline unsigned short f2bf(float x) {
    union { float f; unsigned int u; } c; c.f = x;
    unsigned int r = c.u + 0x7FFFu + ((c.u >> 16) & 1u);   // round-to-nearest-even
    return (unsigned short)(r >> 16);
}

// ------------- Kernel AB (merged): harmonic cols (LDS) -> mel -> log -> bf16 ----
__global__ __launch_bounds__(256) void harm_prep(
    const float* __restrict__ omega,
    const float* __restrict__ stdv,
    const float* __restrict__ mask,
    unsigned short* __restrict__ wT)
{
    int n   = blockIdx.x;            // 0..95 (82..95 = K-pad rows)
    int tid = threadIdx.x;
    if (n >= NNOTES) {               // zero pad rows: (k>=82) x (any y bits) = 0
        wT[tid * KPAD + n] = 0;
        return;
    }
    __shared__ float cols[NFREQ];

    float f0 = 27.5f * exp2f((float)n / 12.0f);
    for (int fi = tid; fi < NFREQ; fi += 256) {
        float f = 11025.0f * (float)fi / 1023.0f;
        const float RAD = 80.0f;                           // 16*sigma at sigma=5
        int klo = (int)ceilf((f - RAD) / f0);
        int khi = (int)floorf((f + RAD) / f0);
        if (klo < 1) klo = 1;
        if (khi > KMAXH) khi = KMAXH;
        float acc = 0.0f;
        for (int k = klo; k <= khi; ++k) {
            int idx = n * KMAXH + (k - 1);
            float mk = mask[idx];
            if (mk == 0.0f) continue;
            float c = f0 * (float)k;
            float s = stdv[idx];
            float d = (f - c) / s;
            float e = 0.5f * d * d;
            if (e > 90.0f) continue;
            acc += omega[idx] * mk * expf(-e);
        }
        cols[fi] = acc;
    }
    __syncthreads();

    int m = tid;
    const float logstep = 0.06875177742094911f;            // log(6.4)/27
    const float mel_max = 15.0f + logf(11.025f) / logstep; // hz_to_mel(11025)
    float mm0 = mel_max * (float)m       / 257.0f;
    float mm1 = mel_max * (float)(m + 1) / 257.0f;
    float mm2 = mel_max * (float)(m + 2) / 257.0f;
    float mf0 = (mm0 >= 15.0f) ? 1000.0f * expf(logstep * (mm0 - 15.0f)) : mm0 * (200.0f / 3.0f);
    float mf1 = (mm1 >= 15.0f) ? 1000.0f * expf(logstep * (mm1 - 15.0f)) : mm1 * (200.0f / 3.0f);
    float mf2 = (mm2 >= 15.0f) ? 1000.0f * expf(logstep * (mm2 - 15.0f)) : mm2 * (200.0f / 3.0f);
    float inv_lo = 1.0f / (mf1 - mf0);
    float inv_hi = 1.0f / (mf2 - mf1);
    float enorm  = 2.0f / (mf2 - mf0);
    int lo = (int)floorf(mf0 * (1024.0f / 11025.0f)) - 1;
    int hi = (int)ceilf (mf2 * (1024.0f / 11025.0f)) + 1;
    if (lo < 0) lo = 0;
    if (hi > 1023) hi = 1023;
    float acc = 0.0f;
    for (int fi = lo; fi <= hi; ++fi) {
        float ff = 11025.0f * (float)(fi + 1) / 1024.0f;
        float wt = fminf((ff - mf0) * inv_lo, (mf2 - ff) * inv_hi);
        wt = fmaxf(0.0f, wt) * enorm;
        acc += wt * cols[fi];
    }
    const float X_MIN = -13.815510557964274f;              // log(1e-6)
    const float X_MAX = 3.0f;
    float x = logf(acc + 1e-6f);
    x = fminf(fmaxf(x, X_MIN), X_MAX);
    wT[m * KPAD + n] = f2bf((x - X_MIN) * (1.0f / (X_MAX - X_MIN)));
}

// ---------------- k1: y f32 -> bf16 fragment array, coalesced both sides --------
// Block = 64 rows (4 x 16-row tiles), 256 threads, grid 2048. Read: contiguous
// float4 per lane (1KB/wave-instr). Scatter cvt_pk'd pairs into 12 KB LDS in
// fragment order; drain with linear ds_read_b128 -> contiguous dwordx4 stores
// (1KB/wave-instr). Pad words (kb=2, k>=82 slots) zeroed by disjoint threads.
__global__ __launch_bounds__(256) void harm_swz(
    const float* __restrict__ y,
    bf16x8* __restrict__ ytmp)
{
    __shared__ unsigned yl[3072];      // 4 tiles x 3 kb x 64 lanes x 4 u32 = 12 KB
    int tid = threadIdx.x;
    size_t blk = blockIdx.x;

    // zero never-written pad words (disjoint from all scatter targets)
    if (tid < 64) {
        int t_loc = tid >> 4, r16 = tid & 15;
        int fi = ((t_loc * 3 + 2) * 64 + r16 + 48) * 4;    // g4=3: all 4 slots
        *(uint4*)&yl[fi] = make_uint4(0u, 0u, 0u, 0u);
    } else if (tid < 128) {
        int q = tid - 64;
        int t_loc = q >> 4, r16 = q & 15;
        int fi = ((t_loc * 3 + 2) * 64 + r16 + 32) * 4;    // g4=2: slots 1..3
        yl[fi + 1] = 0u;
        *(uint2*)&yl[fi + 2] = make_uint2(0u, 0u);
    }

    const float4* ysrc = (const float4*)(y + blk * 5248);  // 1312 float4
    float4 v[6];
    #pragma unroll
    for (int p = 0; p < 5; ++p) v[p] = ysrc[tid + 256 * p];
    if (tid < 32) v[5] = ysrc[1280 + tid];

    #pragma unroll
    for (int p = 0; p < 6; ++p) {
        if (p < 5 || tid < 32) {
            int j = tid + 256 * p;
            #pragma unroll
            for (int h = 0; h < 2; ++h) {
                int e = 4 * j + 2 * h;                     // even flat element
                int r = (int)(((unsigned)e * 51151u) >> 22);   // e/82
                int k = e - 82 * r;
                int t_loc = r >> 4, r16 = r & 15;
                int kb = k >> 5, km = k & 31;
                int idx = ((t_loc * 3 + kb) * 64 + r16 + ((km >> 3) << 4)) * 4
                        + ((km >> 1) & 3);
                float a0 = (h == 0) ? v[p].x : v[p].z;
                float a1 = (h == 0) ? v[p].y : v[p].w;
                unsigned pk;
                asm("v_cvt_pk_bf16_f32 %0, %1, %2" : "=v"(pk) : "v"(a0), "v"(a1));
                yl[idx] = pk;
            }
        }
    }
    __syncthreads();

    bf16x8* dst = ytmp + blk * 768;                        // coalesced drain
    #pragma unroll
    for (int p = 0; p < 3; ++p)
        dst[tid + 256 * p] = *(const bf16x8*)&yl[(tid + 256 * p) * 4];
}

// ---------------- k2: out = ytmp @ w (fill-shaped: 84% write) -------------------
// No LDS, no barriers, no cvt. 12 w-fragments in regs; per 16-row tile:
// 3 coalesced dwordx4 ay loads + 12 MFMA + 16 f32x4 stores. Grid 2048.
__global__ __launch_bounds__(256) void harm_gemm2(
    const bf16x8* __restrict__ ytmp,
    const unsigned short* __restrict__ wT,
    float* __restrict__ out)
{
    int tid  = threadIdx.x;
    int lane = tid & 63;
    int wid  = tid >> 6;
    int r16  = lane & 15;
    int g4   = lane >> 4;
    int c0   = wid * 64;

    bf16x8 bw[3][4];
    #pragma unroll
    for (int kb = 0; kb < 3; ++kb)
        #pragma unroll
        for (int c = 0; c < 4; ++c)
            bw[kb][c] = *(const bf16x8*)(wT + (size_t)(c0 + c * 16 + r16) * KPAD + kb * 32 + g4 * 8);

    size_t tb = (size_t)blockIdx.x * 4;
    #pragma unroll
    for (int i = 0; i < 4; ++i) {
        size_t t = tb + i;
        bf16x8 ay0 = ytmp[(t * 3 + 0) * 64 + lane];
        bf16x8 ay1 = ytmp[(t * 3 + 1) * 64 + lane];
        bf16x8 ay2 = ytmp[(t * 3 + 2) * 64 + lane];
        f32x4 acc[4];
        #pragma unroll
        for (int c = 0; c < 4; ++c) acc[c] = (f32x4){0.f, 0.f, 0.f, 0.f};
        #pragma unroll
        for (int c = 0; c < 4; ++c) acc[c] = __builtin_amdgcn_mfma_f32_16x16x32_bf16(bw[0][c], ay0, acc[c], 0, 0, 0);
        #pragma unroll
        for (int c = 0; c < 4; ++c) acc[c] = __builtin_amdgcn_mfma_f32_16x16x32_bf16(bw[1][c], ay1, acc[c], 0, 0, 0);
        #pragma unroll
        for (int c = 0; c < 4; ++c) acc[c] = __builtin_amdgcn_mfma_f32_16x16x32_bf16(bw[2][c], ay2, acc[c], 0, 0, 0);
        float* orow = out + (t * 16 + r16) * NMELS + c0 + g4 * 4;
        #pragma unroll
        for (int c = 0; c < 4; ++c)
            *(f32x4*)(orow + c * 16) = acc[c];
    }
}

// ---------------- fallback: r13's fused rolling pipeline (if ws too small) ------
__device__ __forceinline__ void gload16(const void* g, void* l) {
    __builtin_amdgcn_global_load_lds(
        (const __attribute__((address_space(1))) unsigned int*)g,
        (__attribute__((address_space(3))) unsigned int*)l, 16, 0, 0);
}

__device__ __forceinline__ void dma_tile(const float* ytile, float* buf, int wid, int lane) {
    int base = wid * 164;
    gload16(ytile + 4 * (base + lane),       buf + 4 * base);
    gload16(ytile + 4 * (base + 64 + lane),  buf + 4 * (base + 64));
    if (lane < 36)
        gload16(ytile + 4 * (base + 128 + lane), buf + 4 * (base + 128));
}

__device__ __forceinline__ void compute_tile32(
    const float* __restrict__ bufp, const bf16x8 bw[3][4],
    float* __restrict__ out, size_t rowbase, int r16, int g4, int c0)
{
    #pragma unroll
    for (int i = 0; i < 2; ++i) {
        const float* yrow = bufp + (i * 16 + r16) * NNOTES;
        bf16x8 ay[3];
        #pragma unroll
        for (int kb = 0; kb < 3; ++kb) {
            const float* fr = yrow + kb * 32 + g4 * 8;
            float2 a0 = *(const float2*)(fr + 0);
            float2 a1 = *(const float2*)(fr + 2);
            float2 a2 = *(const float2*)(fr + 4);
            float2 a3 = *(const float2*)(fr + 6);
            union { unsigned u[4]; bf16x8 v; } A;
            asm("v_cvt_pk_bf16_f32 %0, %1, %2" : "=v"(A.u[0]) : "v"(a0.x), "v"(a0.y));
            asm("v_cvt_pk_bf16_f32 %0, %1, %2" : "=v"(A.u[1]) : "v"(a1.x), "v"(a1.y));
            asm("v_cvt_pk_bf16_f32 %0, %1, %2" : "=v"(A.u[2]) : "v"(a2.x), "v"(a2.y));
            asm("v_cvt_pk_bf16_f32 %0, %1, %2" : "=v"(A.u[3]) : "v"(a3.x), "v"(a3.y));
            ay[kb] = A.v;
        }
        f32x4 acc[4];
        #pragma unroll
        for (int c = 0; c < 4; ++c) acc[c] = (f32x4){0.f, 0.f, 0.f, 0.f};
        #pragma unroll
        for (int kb = 0; kb < 3; ++kb)
            #pragma unroll
            for (int c = 0; c < 4; ++c)
                acc[c] = __builtin_amdgcn_mfma_f32_16x16x32_bf16(bw[kb][c], ay[kb], acc[c], 0, 0, 0);
        float* orow = out + (rowbase + i * 16 + r16) * NMELS + c0 + g4 * 4;
        #pragma unroll
        for (int c = 0; c < 4; ++c)
            *(f32x4*)(orow + c * 16) = acc[c];
    }
}

#define SBAR() do { __builtin_amdgcn_sched_barrier(0); \
                    __builtin_amdgcn_s_barrier(); \
                    __builtin_amdgcn_sched_barrier(0); } while (0)

__global__ __launch_bounds__(256, 4) void harm_gemm(
    const float* __restrict__ y,
    const unsigned short* __restrict__ wT,
    float* __restrict__ out)
{
    __shared__ float yf[3 * BUFSTRIDE];
    int tid  = threadIdx.x;
    int lane = tid & 63;
    int wid  = tid >> 6;
    int r16  = lane & 15;
    int g4   = lane >> 4;
    int c0   = wid * 64;
    size_t t0 = (size_t)blockIdx.x * 4;

    if (tid < 48) yf[(tid >> 4) * BUFSTRIDE + TFLOAT + (tid & 15)] = 0.f;

    bf16x8 bw[3][4];
    #pragma unroll
    for (int kb = 0; kb < 3; ++kb)
        #pragma unroll
        for (int c = 0; c < 4; ++c)
            bw[kb][c] = *(const bf16x8*)(wT + (size_t)(c0 + c * 16 + r16) * KPAD + kb * 32 + g4 * 8);
    __builtin_amdgcn_sched_barrier(0);
    dma_tile(y + (t0 + 0) * TFLOAT, yf + 0 * BUFSTRIDE, wid, lane);
    __builtin_amdgcn_sched_barrier(0);
    dma_tile(y + (t0 + 1) * TFLOAT, yf + 1 * BUFSTRIDE, wid, lane);
    __builtin_amdgcn_sched_barrier(0);

    asm volatile("s_waitcnt vmcnt(3) lgkmcnt(0)" ::: "memory");
    SBAR();
    dma_tile(y + (t0 + 2) * TFLOAT, yf + 2 * BUFSTRIDE, wid, lane);
    __builtin_amdgcn_sched_barrier(0);
    compute_tile32(yf + 0 * BUFSTRIDE, bw, out, (t0 + 0) * TROWS, r16, g4, c0);

    asm volatile("s_waitcnt vmcnt(11)" ::: "memory");
    SBAR();
    dma_tile(y + (t0 + 3) * TFLOAT, yf + 0 * BUFSTRIDE, wid, lane);
    __builtin_amdgcn_sched_barrier(0);
    compute_tile32(yf + 1 * BUFSTRIDE, bw, out, (t0 + 1) * TROWS, r16, g4, c0);

    asm volatile("s_waitcnt vmcnt(19)" ::: "memory");
    SBAR();
    compute_tile32(yf + 2 * BUFSTRIDE, bw, out, (t0 + 2) * TROWS, r16, g4, c0);

    asm volatile("s_waitcnt vmcnt(16)" ::: "memory");
    SBAR();
    compute_tile32(yf + 0 * BUFSTRIDE, bw, out, (t0 + 3) * TROWS, r16, g4, c0);
}

extern "C" void kernel_launch(void* const* d_in, const int* in_sizes, int n_in,
                              void* d_out, int out_size, void* d_ws, size_t ws_size,
                              hipStream_t stream) {
    const float* y     = (const float*)d_in[0];
    const float* omega = (const float*)d_in[1];
    const float* stdv  = (const float*)d_in[2];
    const float* mask  = (const float*)d_in[3];
    float* out = (float*)d_out;

    unsigned short* wT = (unsigned short*)d_ws;           // 256*96 bf16 = 48 KB
    int R      = in_sizes[0] / NNOTES;                    // 131072 rows
    int ntiles = R / 16;                                  // 8192
    size_t wT_bytes   = (size_t)NMELS * KPAD * 2;
    size_t ytmp_bytes = (size_t)ntiles * 3 * 64 * 16;     // 25.2 MB
    bf16x8* ytmp = (bf16x8*)((char*)d_ws + wT_bytes);

    harm_prep<<<KPAD, 256, 0, stream>>>(omega, stdv, mask, wT);

    if (ws_size >= wT_bytes + ytmp_bytes) {
        harm_swz  <<<R / 64,     256, 0, stream>>>(y, ytmp);
        harm_gemm2<<<ntiles / 4, 256, 0, stream>>>(ytmp, wT, out);
    } else {
        harm_gemm<<<R / 128, 256, 0, stream>>>(y, wT, out);  // r13 fallback
    }
}